// Round 1
// 85.532 us; speedup vs baseline: 1.0953x; 1.0953x over previous
//
#include <hip/hip_runtime.h>

// VQC NQ=4, NL=1, B=1048576 — Heisenberg-picture collapse.
//
// z_q = <psi| C^dag O_q C |psi>,  O_q = al*Z + A*X + B*Y  (phi drops out),
//   al = cos(th), A = -sin(th)cos(lm), B = sin(th)sin(lm)
// C = CNOT(0,1)CNOT(1,2)CNOT(2,3)CNOT(3,0); conjugated Pauli strings
// (stabilizer tableau, verified two independent ways incl. the -1 on q3 Y):
//   q0: Z->Z1Z2Z3,   X->X0X1,     Y->X0Y1Z2Z3
//   q1: Z->Z0Z1,     X->X1X2,     Y->Z0Y1X2
//   q2: Z->Z0Z1Z2,   X->X2X3,     Y->Z0Z1Y2X3
//   q3: Z->Z0Z1Z2Z3, X->X0X1X3,   Y->-Y0Y1Z2Y3
// |psi> = product state => E[string] = prod_r <P_r> : only per-qubit Bloch
// vectors needed. Bloch of RZ(g)RY(b)RZ(a)|+> (FULL angles):
//   x = ca*cb*cg - sa*sg;  y = ca*cb*sg + sa*cg;  z = -ca*sb
// Eliminates the 16-amplitude state, CNOT permutation, 16 probabilities and
// 32 coherence pairs: ~60 VALU + 12 sincos/thread vs ~500 VALU before.
// vqc_prep fused in (4 threads/block -> LDS broadcast); workspace unused.

__global__ __launch_bounds__(256) void vqc_main(const float4* __restrict__ enc,
                                                const float* __restrict__ w,
                                                float4* __restrict__ out, int B) {
    __shared__ float wal[4], wA[4], wB[4];
    const int t = threadIdx.x;
    const int b = blockIdx.x * blockDim.x + t;

    // uniform measurement coefficients: 4 threads compute, LDS-broadcast
    if (t < 4) {
        float th = w[t * 3 + 0];
        float lm = w[t * 3 + 2];   // w[t*3+1] (phi) provably drops out of <Z_q>
        float st, ct, sl, cl;
        __sincosf(th, &st, &ct);
        __sincosf(lm, &sl, &cl);
        wal[t] = ct;
        wA[t] = -st * cl;
        wB[t] = st * sl;
    }

    // issue the (per-thread) enc loads before the barrier so HBM latency
    // overlaps the weight sincos
    const bool live = (b < B);
    float4 e0, e1, e2;
    if (live) {
        e0 = enc[b * 3 + 0];
        e1 = enc[b * 3 + 1];
        e2 = enc[b * 3 + 2];
    }
    __syncthreads();
    if (!live) return;

    const float ang[12] = {e0.x, e0.y, e0.z, e0.w, e1.x, e1.y, e1.z, e1.w,
                           e2.x, e2.y, e2.z, e2.w};

    // per-qubit Bloch vector of the encoded state
    float x[4], y[4], z[4];
#pragma unroll
    for (int q = 0; q < 4; ++q) {
        float sa, ca, sb, cb, sg, cg;
        __sincosf(ang[3 * q + 0], &sa, &ca);
        __sincosf(ang[3 * q + 1], &sb, &cb);
        __sincosf(ang[3 * q + 2], &sg, &cg);
        float cc = ca * cb;
        x[q] = cc * cg - sa * sg;
        y[q] = cc * sg + sa * cg;
        z[q] = -ca * sb;
    }

    // shared monomials
    const float z23   = z[2] * z[3];
    const float z123  = z[1] * z23;
    const float z01   = z[0] * z[1];
    const float z012  = z01 * z[2];
    const float z0123 = z012 * z[3];
    const float x01   = x[0] * x[1];

    const float o0 = wal[0] * z123  + wA[0] * x01           + wB[0] * (x[0] * (y[1] * z23));
    const float o1 = wal[1] * z01   + wA[1] * (x[1] * x[2]) + wB[1] * ((z[0] * y[1]) * x[2]);
    const float o2 = wal[2] * z012  + wA[2] * (x[2] * x[3]) + wB[2] * ((z01 * y[2]) * x[3]);
    const float o3 = wal[3] * z0123 + wA[3] * (x01 * x[3])  - wB[3] * (((y[0] * y[1]) * z[2]) * y[3]);

    out[b] = make_float4(o0, o1, o2, o3);
}

extern "C" void kernel_launch(void* const* d_in, const int* in_sizes, int n_in,
                              void* d_out, int out_size, void* d_ws, size_t ws_size,
                              hipStream_t stream) {
    const float* enc = (const float*)d_in[0];   // (B, 4, 3) f32
    const float* w   = (const float*)d_in[1];   // (1, 4, 3) f32
    float* out = (float*)d_out;                 // (B, 4) f32
    (void)d_ws; (void)ws_size;

    int B = in_sizes[0] / 12;
    int grid = (B + 255) / 256;
    vqc_main<<<grid, 256, 0, stream>>>((const float4*)enc, w, (float4*)out, B);
}